// Round 10
// baseline (190.266 us; speedup 1.0000x reference)
//
#include <hip/hip_runtime.h>

// ---------------------------------------------------------------------------
// EfficentLePE, block-local: block = (window w, head-pair g).
// Window = [128 rows x 8 cols] tokens; head h <-> channels [h*16,(h+1)*16).
//   A[h] = softmax_e( SCALE * sum_n K[n,d] V[n,e] )   (16x16)
//   out[n,e] = sum_d Q[n,d] A[h][d,e] + depthwise3x3(Q)[n,e] + bias
// R4 structure. Single change vs R4 (best, 55.3us): LDS 66KB -> 38KB so
// 4 blocks/CU co-reside (R8 profile: occupancy 21%, VALU 16%, HBM 19% ->
// latency-bound). Pass-1 K/V tiles shrink 16->8 rows (dbuf 64KB -> 32KB);
// pass-2 is verbatim R4.
// ---------------------------------------------------------------------------

static constexpr int BB   = 8;
static constexpr int RES  = 128;
static constexpr int DIM  = 128;
static constexpr int WSP  = 8;
static constexpr int L    = RES * RES;   // 16384
static constexpr int ROWSTRIDE = RES * DIM;
static constexpr float SCALE = 0.25f;    // HD^-0.5, HD=16

#define GLD_LDS16(g, l)                                                        \
  __builtin_amdgcn_global_load_lds(                                            \
      (const __attribute__((address_space(1))) void*)(const void*)(g),         \
      (__attribute__((address_space(3))) void*)(l), 16, 0, 0)

__global__ __launch_bounds__(256, 4) void fused_lepe(
    const float* __restrict__ Qg, const float* __restrict__ Kg,
    const float* __restrict__ Vg, const float* __restrict__ cw,
    const float* __restrict__ cb, float* __restrict__ outp) {
  // smem map (floats), total 9728 = 38 KB:
  //  pass1: K dbuf [0,4096) (2 x 2048), V dbuf [4096,8192)
  //  scratch [0,2048)                  (after pass1; K buf dead)
  //  pass2: Qbuf0 [0,4608), Qbuf1 [4608,9216)   (Qbuf1 over dead V buf)
  //  A_sm  [9216,9728)
  __shared__ float smem[9728];
  float* const A_sm    = smem + 9216;
  float* const scratch = smem;

  const int b  = blockIdx.x;            // 0..511
  const int w  = b >> 2, g = b & 3;     // window, head-group (2 heads)
  const int bi = w >> 4, wb = w & 15;   // batch, window-col
  const int t  = threadIdx.x;
  const int wave = t >> 6, lane = t & 63;
  const size_t win_base = (size_t)(bi * L + wb * WSP) * DIM;
  const int ch0 = g * 32;               // first global channel of this group

  // ======== Pass 1: Gram = K^T V, 16 tiles of 8 image rows ================
  // accum mapping per wave: h1 = lane>>5, dq=(lane>>3)&3, ep=lane&7
  const int h1 = lane >> 5, dq = (lane >> 3) & 3, ep = lane & 7;
  const int kaddr = h1 * 16 + dq * 4;
  const int vaddr = h1 * 16 + ep * 2;
  const int n0 = wave * 16;             // this wave's 16 tokens of the tile

  float a00=0.f,a01=0.f,a10=0.f,a11=0.f,a20=0.f,a21=0.f,a30=0.f,a31=0.f;

  auto stageKV = [&](int tile, int buf) {
    // 16 chunks: mat (K/V) x 8 rows; 4 per wave. Chunk = 8 tokens x 32 ch.
    for (int c = wave; c < 16; c += 4) {
      const int mat = c >> 3, rr = c & 7;
      const int r = tile * 8 + rr;      // image row
      const float* src = (mat ? Vg : Kg) + win_base +
                         (size_t)r * ROWSTRIDE + (lane >> 3) * DIM + ch0 +
                         (lane & 7) * 4;
      float* dst = smem + mat * 4096 + buf * 2048 + rr * 256;
      GLD_LDS16(src, dst);
    }
  };

  stageKV(0, 0);
  __syncthreads();
  for (int tt = 0; tt < 16; ++tt) {
    const int cur = tt & 1;
    if (tt < 15) stageKV(tt + 1, cur ^ 1);
    const float* Kb = smem + cur * 2048;
    const float* Vb = smem + 4096 + cur * 2048;
#pragma unroll 4
    for (int n = n0; n < n0 + 16; ++n) {
      const float4 k4 = *reinterpret_cast<const float4*>(&Kb[n * 32 + kaddr]);
      const float2 v2 = *reinterpret_cast<const float2*>(&Vb[n * 32 + vaddr]);
      a00 += k4.x * v2.x; a01 += k4.x * v2.y;
      a10 += k4.y * v2.x; a11 += k4.y * v2.y;
      a20 += k4.z * v2.x; a21 += k4.z * v2.y;
      a30 += k4.w * v2.x; a31 += k4.w * v2.y;
    }
    __syncthreads();
  }

  // ======== Q-tile staging helper (18 rows incl. halos, zero off-image) ===
  auto stageQ = [&](int tile, int buf) {
    const int r0 = tile * 16;
    float* qb = smem + buf * 4608;
    for (int c = wave; c < 18; c += 4) {
      const int r = r0 - 1 + c;         // image row for buffer row c
      float* dst = qb + c * 256;
      if ((unsigned)r < 128u) {
        const float* src = Qg + win_base + (size_t)r * ROWSTRIDE +
                           (lane >> 3) * DIM + ch0 + (lane & 7) * 4;
        GLD_LDS16(src, dst);
      } else {
        *reinterpret_cast<float4*>(dst + lane * 4) =
            make_float4(0.f, 0.f, 0.f, 0.f);
      }
    }
  };

  // issue Q tile 0 into buf1 (over dead V dbuf), then write Gram partials
  stageQ(0, 1);
  {
    float* sc = scratch + wave * 512 + lane * 8;
    sc[0]=a00; sc[1]=a01; sc[2]=a10; sc[3]=a11;
    sc[4]=a20; sc[5]=a21; sc[6]=a30; sc[7]=a31;
  }
  __syncthreads();                       // scratch visible

  // ======== reduce 4 wave-copies + softmax over e -> A_sm[h*16+d][e] ======
  {
    const int r = t >> 3, e2 = t & 7;    // r = h*16+d, e in {2e2, 2e2+1}
    const int h = r >> 4, d = r & 15;
    const int f = (h * 32 + (d >> 2) * 8 + e2) * 8 + (d & 3) * 2;
    float v0 = (scratch[f]     + scratch[512 + f]     + scratch[1024 + f]     + scratch[1536 + f]) * SCALE;
    float v1 = (scratch[f + 1] + scratch[512 + f + 1] + scratch[1024 + f + 1] + scratch[1536 + f + 1]) * SCALE;
    float m = fmaxf(v0, v1);
    m = fmaxf(m, __shfl_xor(m, 1));
    m = fmaxf(m, __shfl_xor(m, 2));
    m = fmaxf(m, __shfl_xor(m, 4));
    v0 = __expf(v0 - m); v1 = __expf(v1 - m);
    float ss = v0 + v1;
    ss += __shfl_xor(ss, 1);
    ss += __shfl_xor(ss, 2);
    ss += __shfl_xor(ss, 4);
    const float ri = 1.0f / ss;
    A_sm[r * 16 + e2 * 2 + 0] = v0 * ri;
    A_sm[r * 16 + e2 * 2 + 1] = v1 * ri;
  }
  __syncthreads();                       // A_sm ready; Q tile 0 drained

  // ======== Pass 2 setup: per-thread A column, conv weights, bias =========
  const int cq   = t & 7;                // channel quad (4 ch) within 32
  const int lr   = (t >> 3) & 15;        // local output row in tile
  const int half = t >> 7;               // wl range: half*4 .. half*4+3
  const int hg = cq >> 2, e0 = (cq & 3) * 4;
  const int cg = ch0 + cq * 4;           // global channel quad base

  float4 Acol[16];
#pragma unroll
  for (int d = 0; d < 16; ++d)
    Acol[d] = *reinterpret_cast<const float4*>(&A_sm[(hg * 16 + d) * 16 + e0]);
  float4 wgt[9];
#pragma unroll
  for (int tap = 0; tap < 9; ++tap) {
    wgt[tap].x = cw[(cg + 0) * 9 + tap];
    wgt[tap].y = cw[(cg + 1) * 9 + tap];
    wgt[tap].z = cw[(cg + 2) * 9 + tap];
    wgt[tap].w = cw[(cg + 3) * 9 + tap];
  }
  const float4 bias = *reinterpret_cast<const float4*>(&cb[cg]);
  const float4 zero4 = make_float4(0.f, 0.f, 0.f, 0.f);

#define ACC(qs, d)                                                             \
  o.x += (qs) * Acol[d].x; o.y += (qs) * Acol[d].y;                            \
  o.z += (qs) * Acol[d].z; o.w += (qs) * Acol[d].w;

  // ======== Pass 2 main loop: 8 tiles of 16 rows, double-buffered =========
  int buf = 1;
  for (int tile = 0; tile < 8; ++tile) {
    if (tile < 7) stageQ(tile + 1, buf ^ 1);
    const float* Qb = smem + buf * 4608;
    const int r0 = tile * 16;
    const int w0 = half * 4;

    float4 cL[3], cC[3], cR[3];
    auto ldcol = [&](int cidx, float4* dv) {
#pragma unroll
      for (int dy = 0; dy < 3; ++dy)
        dv[dy] = ((unsigned)cidx < 8u)
                     ? *reinterpret_cast<const float4*>(
                           &Qb[((lr + dy) * 8 + cidx) * 32 + cq * 4])
                     : zero4;
    };
    ldcol(w0 - 1, cL);
    ldcol(w0, cC);

#pragma unroll
    for (int k = 0; k < 4; ++k) {
      const int wl = w0 + k;
      ldcol(wl + 1, cR);
      float4 o = bias;
#pragma unroll
      for (int dy = 0; dy < 3; ++dy) {
        const int t0 = dy * 3;
        o.x += cL[dy].x * wgt[t0].x + cC[dy].x * wgt[t0+1].x + cR[dy].x * wgt[t0+2].x;
        o.y += cL[dy].y * wgt[t0].y + cC[dy].y * wgt[t0+1].y + cR[dy].y * wgt[t0+2].y;
        o.z += cL[dy].z * wgt[t0].z + cC[dy].z * wgt[t0+1].z + cR[dy].z * wgt[t0+2].z;
        o.w += cL[dy].w * wgt[t0].w + cC[dy].w * wgt[t0+1].w + cR[dy].w * wgt[t0+2].w;
      }
      // attention: Q[token, hg*16..+15] . Acol  (token buffer row = lr+1)
      const float* qr = &Qb[((lr + 1) * 8 + wl) * 32 + hg * 16];
      const float4 q0 = *reinterpret_cast<const float4*>(qr + 0);
      const float4 q1 = *reinterpret_cast<const float4*>(qr + 4);
      const float4 q2 = *reinterpret_cast<const float4*>(qr + 8);
      const float4 q3 = *reinterpret_cast<const float4*>(qr + 12);
      ACC(q0.x, 0)  ACC(q0.y, 1)  ACC(q0.z, 2)  ACC(q0.w, 3)
      ACC(q1.x, 4)  ACC(q1.y, 5)  ACC(q1.z, 6)  ACC(q1.w, 7)
      ACC(q2.x, 8)  ACC(q2.y, 9)  ACC(q2.z, 10) ACC(q2.w, 11)
      ACC(q3.x, 12) ACC(q3.y, 13) ACC(q3.z, 14) ACC(q3.w, 15)

      float* dst = outp + win_base + (size_t)(r0 + lr) * ROWSTRIDE +
                   wl * DIM + cg;
      *reinterpret_cast<float4*>(dst) = o;

#pragma unroll
      for (int dy = 0; dy < 3; ++dy) { cL[dy] = cC[dy]; cC[dy] = cR[dy]; }
    }
    __syncthreads();
    buf ^= 1;
  }
#undef ACC
}

// ---------------------------------------------------------------------------
extern "C" void kernel_launch(void* const* d_in, const int* in_sizes, int n_in,
                              void* d_out, int out_size, void* d_ws,
                              size_t ws_size, hipStream_t stream) {
  const float* qkv = (const float*)d_in[0];
  const float* cw  = (const float*)d_in[1];
  const float* cb  = (const float*)d_in[2];
  const float* Qg = qkv;
  const float* Kg = qkv + (size_t)BB * L * DIM;
  const float* Vg = Kg + (size_t)BB * L * DIM;
  float* outp = (float*)d_out;

  fused_lepe<<<512, 256, 0, stream>>>(Qg, Kg, Vg, cw, cb, outp);
}

// Round 11
// 188.806 us; speedup vs baseline: 1.0077x; 1.0077x over previous
//
#include <hip/hip_runtime.h>

// ---------------------------------------------------------------------------
// EfficentLePE, block-local: block = (window w, head-pair g), 512 threads.
// Window = [128 rows x 8 cols] tokens; head h <-> channels [h*16,(h+1)*16).
//   A[h] = softmax_e( SCALE * sum_n K[n,d] V[n,e] )   (16x16)
//   out[n,e] = sum_d Q[n,d] A[h][d,e] + depthwise3x3(Q)[n,e] + bias
// vs R4 (best, 55.3us): (1) 512-thread blocks -> 16 waves/CU (grid 512 =
// exactly 2 blocks/CU; R8 profile showed latency-bound at 8 waves/CU);
// (2) pass-2 XOR swizzle (validated in R5) kills the measured 3.47M 8-way
// LDS conflicts. Same LDS map (66KB), same algorithm, same staging.
// R10 lesson applied: launch_bounds VGPR cap 128 >= ~100 actual need.
// ---------------------------------------------------------------------------

static constexpr int BB   = 8;
static constexpr int RES  = 128;
static constexpr int DIM  = 128;
static constexpr int WSP  = 8;
static constexpr int L    = RES * RES;   // 16384
static constexpr int ROWSTRIDE = RES * DIM;
static constexpr float SCALE = 0.25f;    // HD^-0.5, HD=16

#define GLD_LDS16(g, l)                                                        \
  __builtin_amdgcn_global_load_lds(                                            \
      (const __attribute__((address_space(1))) void*)(const void*)(g),         \
      (__attribute__((address_space(3))) void*)(l), 16, 0, 0)

__global__ __launch_bounds__(512, 4) void fused_lepe(
    const float* __restrict__ Qg, const float* __restrict__ Kg,
    const float* __restrict__ Vg, const float* __restrict__ cw,
    const float* __restrict__ cb, float* __restrict__ outp) {
  // smem map (floats):
  //  pass1: K dbuf [0,8192) (2 x 4096), V dbuf [8192,16384)
  //  scratch [0,4096)                  (after pass1; K dbuf dead)
  //  pass2: Qbuf0 [0,4608), Qbuf1 [4608,9216)
  //  A_sm  [16384,16896)
  __shared__ float smem[16896];
  float* const A_sm    = smem + 16384;
  float* const scratch = smem;

  const int b  = blockIdx.x;            // 0..511
  const int w  = b >> 2, g = b & 3;     // window, head-group (2 heads)
  const int bi = w >> 4, wb = w & 15;   // batch, window-col
  const int t  = threadIdx.x;           // 0..511
  const int wave = t >> 6, lane = t & 63;
  const size_t win_base = (size_t)(bi * L + wb * WSP) * DIM;
  const int ch0 = g * 32;               // first global channel of this group

  // ======== Pass 1: Gram = K^T V, 8 tiles of 16 image rows ================
  // accum mapping per wave: h1 = lane>>5, dq=(lane>>3)&3, ep=lane&7
  const int h1 = lane >> 5, dq = (lane >> 3) & 3, ep = lane & 7;
  const int kaddr = h1 * 16 + dq * 4;
  const int vaddr = h1 * 16 + ep * 2;
  const int n0 = wave * 16;             // this wave's token-eighth of tile

  float a00=0.f,a01=0.f,a10=0.f,a11=0.f,a20=0.f,a21=0.f,a30=0.f,a31=0.f;

  auto stageKV = [&](int tile, int buf) {
    // 32 chunks: mat (K/V) x 16 rows; 4 per wave. Chunk = 8 tokens x 32 ch.
    for (int c = wave; c < 32; c += 8) {
      const int mat = c >> 4, rr = c & 15;
      const int r = tile * 16 + rr;     // image row
      const float* src = (mat ? Vg : Kg) + win_base +
                         (size_t)r * ROWSTRIDE + (lane >> 3) * DIM + ch0 +
                         (lane & 7) * 4;
      float* dst = smem + mat * 8192 + buf * 4096 + rr * 256;
      GLD_LDS16(src, dst);
    }
  };

  stageKV(0, 0);
  __syncthreads();
  for (int tt = 0; tt < 8; ++tt) {
    const int cur = tt & 1;
    if (tt < 7) stageKV(tt + 1, cur ^ 1);
    const float* Kb = smem + cur * 4096;
    const float* Vb = smem + 8192 + cur * 4096;
#pragma unroll 4
    for (int n = n0; n < n0 + 16; ++n) {
      const float4 k4 = *reinterpret_cast<const float4*>(&Kb[n * 32 + kaddr]);
      const float2 v2 = *reinterpret_cast<const float2*>(&Vb[n * 32 + vaddr]);
      a00 += k4.x * v2.x; a01 += k4.x * v2.y;
      a10 += k4.y * v2.x; a11 += k4.y * v2.y;
      a20 += k4.z * v2.x; a21 += k4.z * v2.y;
      a30 += k4.w * v2.x; a31 += k4.w * v2.y;
    }
    __syncthreads();
  }

  // ======== Q-tile staging (18 rows incl. halos, XOR-swizzled quads) ======
  auto stageQ = [&](int tile, int buf) {
    const int r0 = tile * 16;
    float* qb = smem + buf * 4608;
    for (int c = wave; c < 18; c += 8) {
      const int r = r0 - 1 + c;         // image row for buffer row c
      float* dst = qb + c * 256;
      if ((unsigned)r < 128u) {
        const float* src = Qg + win_base + (size_t)r * ROWSTRIDE +
                           (lane >> 3) * DIM + ch0 +
                           (((lane & 7) ^ (c & 7)) << 2);   // pre-swizzled src
        GLD_LDS16(src, dst);
      } else {
        *reinterpret_cast<float4*>(dst + lane * 4) =
            make_float4(0.f, 0.f, 0.f, 0.f);
      }
    }
  };

  // issue Q tile 0 into buf1 (latency hides under reduce), write partials
  stageQ(0, 1);
  {
    float* sc = scratch + wave * 512 + lane * 8;
    sc[0]=a00; sc[1]=a01; sc[2]=a10; sc[3]=a11;
    sc[4]=a20; sc[5]=a21; sc[6]=a30; sc[7]=a31;
  }
  __syncthreads();                       // scratch visible

  // ======== reduce 8 wave-copies + softmax over e -> A_sm[h*16+d][e] ======
  {
    const int r = t >> 4;                // 0..31 = h*16+d
    const int e = t & 15;                // 0..15
    const int h = r >> 4, d = r & 15;
    const int f = (h * 32 + (d >> 2) * 8 + (e >> 1)) * 8 + (d & 3) * 2 + (e & 1);
    float v = 0.f;
#pragma unroll
    for (int k = 0; k < 8; ++k) v += scratch[k * 512 + f];
    v *= SCALE;
    float m = v;
    m = fmaxf(m, __shfl_xor(m, 1));
    m = fmaxf(m, __shfl_xor(m, 2));
    m = fmaxf(m, __shfl_xor(m, 4));
    m = fmaxf(m, __shfl_xor(m, 8));
    v = __expf(v - m);
    float ss = v;
    ss += __shfl_xor(ss, 1);
    ss += __shfl_xor(ss, 2);
    ss += __shfl_xor(ss, 4);
    ss += __shfl_xor(ss, 8);
    A_sm[r * 16 + e] = v / ss;
  }
  __syncthreads();                       // A_sm ready; Q tile 0 drained

  // ======== Pass 2 setup: per-thread A column, conv weights, bias =========
  const int cq      = t & 7;             // channel quad (4 ch) within 32
  const int lr      = (t >> 3) & 15;     // local output row in tile
  const int quarter = t >> 7;            // wl range: quarter*2 .. +1
  const int hg = cq >> 2, e0 = (cq & 3) * 4;
  const int cg = ch0 + cq * 4;           // global channel quad base

  float4 Acol[16];
#pragma unroll
  for (int d = 0; d < 16; ++d)
    Acol[d] = *reinterpret_cast<const float4*>(&A_sm[(hg * 16 + d) * 16 + e0]);
  float4 wgt[9];
#pragma unroll
  for (int tap = 0; tap < 9; ++tap) {
    wgt[tap].x = cw[(cg + 0) * 9 + tap];
    wgt[tap].y = cw[(cg + 1) * 9 + tap];
    wgt[tap].z = cw[(cg + 2) * 9 + tap];
    wgt[tap].w = cw[(cg + 3) * 9 + tap];
  }
  const float4 bias = *reinterpret_cast<const float4*>(&cb[cg]);
  const float4 zero4 = make_float4(0.f, 0.f, 0.f, 0.f);

#define ACC(qs, d)                                                             \
  o.x += (qs) * Acol[d].x; o.y += (qs) * Acol[d].y;                            \
  o.z += (qs) * Acol[d].z; o.w += (qs) * Acol[d].w;

  // ======== Pass 2 main loop: 8 tiles of 16 rows, double-buffered =========
  int buf = 1;
  for (int tile = 0; tile < 8; ++tile) {
    if (tile < 7) stageQ(tile + 1, buf ^ 1);
    const float* Qb = smem + buf * 4608;
    const int r0 = tile * 16;
    const int w0 = quarter * 2;

    float4 cL[3], cC[3], cR[3];
    auto ldcol = [&](int cidx, float4* dv) {
#pragma unroll
      for (int dy = 0; dy < 3; ++dy) {
        const int br = lr + dy;          // buffer row
        dv[dy] = ((unsigned)cidx < 8u)
                     ? *reinterpret_cast<const float4*>(
                           &Qb[(br * 8 + cidx) * 32 + ((cq ^ (br & 7)) << 2)])
                     : zero4;
      }
    };
    ldcol(w0 - 1, cL);
    ldcol(w0, cC);

#pragma unroll
    for (int k = 0; k < 2; ++k) {
      const int wl = w0 + k;
      ldcol(wl + 1, cR);
      float4 o = bias;
#pragma unroll
      for (int dy = 0; dy < 3; ++dy) {
        const int t0 = dy * 3;
        o.x += cL[dy].x * wgt[t0].x + cC[dy].x * wgt[t0+1].x + cR[dy].x * wgt[t0+2].x;
        o.y += cL[dy].y * wgt[t0].y + cC[dy].y * wgt[t0+1].y + cR[dy].y * wgt[t0+2].y;
        o.z += cL[dy].z * wgt[t0].z + cC[dy].z * wgt[t0+1].z + cR[dy].z * wgt[t0+2].z;
        o.w += cL[dy].w * wgt[t0].w + cC[dy].w * wgt[t0+1].w + cR[dy].w * wgt[t0+2].w;
      }
      // attention: Q[token, head hg] . Acol   (buffer row lr+1, swizzled)
      {
        const int sw = (lr + 1) & 7;
        const float* qb0 = &Qb[((lr + 1) * 8 + wl) * 32];
        const float4 q0 = *reinterpret_cast<const float4*>(qb0 + (((hg*4+0)^sw)<<2));
        const float4 q1 = *reinterpret_cast<const float4*>(qb0 + (((hg*4+1)^sw)<<2));
        const float4 q2 = *reinterpret_cast<const float4*>(qb0 + (((hg*4+2)^sw)<<2));
        const float4 q3 = *reinterpret_cast<const float4*>(qb0 + (((hg*4+3)^sw)<<2));
        ACC(q0.x, 0)  ACC(q0.y, 1)  ACC(q0.z, 2)  ACC(q0.w, 3)
        ACC(q1.x, 4)  ACC(q1.y, 5)  ACC(q1.z, 6)  ACC(q1.w, 7)
        ACC(q2.x, 8)  ACC(q2.y, 9)  ACC(q2.z, 10) ACC(q2.w, 11)
        ACC(q3.x, 12) ACC(q3.y, 13) ACC(q3.z, 14) ACC(q3.w, 15)
      }
      float* dst = outp + win_base + (size_t)(r0 + lr) * ROWSTRIDE +
                   wl * DIM + cg;
      *reinterpret_cast<float4*>(dst) = o;

#pragma unroll
      for (int dy = 0; dy < 3; ++dy) { cL[dy] = cC[dy]; cC[dy] = cR[dy]; }
    }
    __syncthreads();
    buf ^= 1;
  }
#undef ACC
}

// ---------------------------------------------------------------------------
extern "C" void kernel_launch(void* const* d_in, const int* in_sizes, int n_in,
                              void* d_out, int out_size, void* d_ws,
                              size_t ws_size, hipStream_t stream) {
  const float* qkv = (const float*)d_in[0];
  const float* cw  = (const float*)d_in[1];
  const float* cb  = (const float*)d_in[2];
  const float* Qg = qkv;
  const float* Kg = qkv + (size_t)BB * L * DIM;
  const float* Vg = Kg + (size_t)BB * L * DIM;
  float* outp = (float*)d_out;

  fused_lepe<<<512, 512, 0, stream>>>(Qg, Kg, Vg, cw, cb, outp);
}

// Round 12
// 73.136 us; speedup vs baseline: 2.6015x; 2.5816x over previous
//
#include <hip/hip_runtime.h>

// ---------------------------------------------------------------------------
// EfficentLePE, block-local: block = (window w, head-pair g), 512 threads.
// Window = [128 rows x 8 cols] tokens; head h <-> channels [h*16,(h+1)*16).
//   A[h] = softmax_e( SCALE * sum_n K[n,d] V[n,e] )   (16x16)
//   out[n,e] = sum_d Q[n,d] A[h][d,e] + depthwise3x3(Q)[n,e] + bias
// R4 algorithm + addressing (best known, 55.3us), 512-thread blocks:
// grid 512 = 2 blocks/CU x 8 waves = 16 waves/CU (R8: latency-bound at 8).
// __launch_bounds__(512,2): empirically (_,4) clamps to 64 VGPR -> spills
// (R10/R11 disasters); (_,2) lets the allocator sit at ~100 like R4.
// No swizzle: R11 proved it doesn't move SQ_LDS_BANK_CONFLICT (~5% cost).
// ---------------------------------------------------------------------------

static constexpr int BB   = 8;
static constexpr int RES  = 128;
static constexpr int DIM  = 128;
static constexpr int WSP  = 8;
static constexpr int L    = RES * RES;   // 16384
static constexpr int ROWSTRIDE = RES * DIM;
static constexpr float SCALE = 0.25f;    // HD^-0.5, HD=16

#define GLD_LDS16(g, l)                                                        \
  __builtin_amdgcn_global_load_lds(                                            \
      (const __attribute__((address_space(1))) void*)(const void*)(g),         \
      (__attribute__((address_space(3))) void*)(l), 16, 0, 0)

__global__ __launch_bounds__(512, 2) void fused_lepe(
    const float* __restrict__ Qg, const float* __restrict__ Kg,
    const float* __restrict__ Vg, const float* __restrict__ cw,
    const float* __restrict__ cb, float* __restrict__ outp) {
  // smem map (floats):
  //  pass1: K dbuf [0,8192) (2 x 4096), V dbuf [8192,16384)
  //  scratch [0,4096)                  (after pass1; K dbuf dead)
  //  pass2: Qbuf0 [0,4608), Qbuf1 [4608,9216)
  //  A_sm  [16384,16896)
  __shared__ float smem[16896];
  float* const A_sm    = smem + 16384;
  float* const scratch = smem;

  const int b  = blockIdx.x;            // 0..511
  const int w  = b >> 2, g = b & 3;     // window, head-group (2 heads)
  const int bi = w >> 4, wb = w & 15;   // batch, window-col
  const int t  = threadIdx.x;           // 0..511
  const int wave = t >> 6, lane = t & 63;
  const size_t win_base = (size_t)(bi * L + wb * WSP) * DIM;
  const int ch0 = g * 32;               // first global channel of this group

  // ======== Pass 1: Gram = K^T V, 8 tiles of 16 image rows ================
  // accum mapping per wave: h1 = lane>>5, dq=(lane>>3)&3, ep=lane&7
  const int h1 = lane >> 5, dq = (lane >> 3) & 3, ep = lane & 7;
  const int kaddr = h1 * 16 + dq * 4;
  const int vaddr = h1 * 16 + ep * 2;
  const int n0 = wave * 16;             // this wave's token-eighth of tile

  float a00=0.f,a01=0.f,a10=0.f,a11=0.f,a20=0.f,a21=0.f,a30=0.f,a31=0.f;

  auto stageKV = [&](int tile, int buf) {
    // 32 chunks: mat (K/V) x 16 rows; 4 per wave. Chunk = 8 tokens x 32 ch.
    for (int c = wave; c < 32; c += 8) {
      const int mat = c >> 4, rr = c & 15;
      const int r = tile * 16 + rr;     // image row
      const float* src = (mat ? Vg : Kg) + win_base +
                         (size_t)r * ROWSTRIDE + (lane >> 3) * DIM + ch0 +
                         (lane & 7) * 4;
      float* dst = smem + mat * 8192 + buf * 4096 + rr * 256;
      GLD_LDS16(src, dst);
    }
  };

  stageKV(0, 0);
  __syncthreads();
  for (int tt = 0; tt < 8; ++tt) {
    const int cur = tt & 1;
    if (tt < 7) stageKV(tt + 1, cur ^ 1);
    const float* Kb = smem + cur * 4096;
    const float* Vb = smem + 8192 + cur * 4096;
#pragma unroll 4
    for (int n = n0; n < n0 + 16; ++n) {
      const float4 k4 = *reinterpret_cast<const float4*>(&Kb[n * 32 + kaddr]);
      const float2 v2 = *reinterpret_cast<const float2*>(&Vb[n * 32 + vaddr]);
      a00 += k4.x * v2.x; a01 += k4.x * v2.y;
      a10 += k4.y * v2.x; a11 += k4.y * v2.y;
      a20 += k4.z * v2.x; a21 += k4.z * v2.y;
      a30 += k4.w * v2.x; a31 += k4.w * v2.y;
    }
    __syncthreads();
  }

  // ======== Q-tile staging (18 rows incl. halos, R4 plain layout) =========
  auto stageQ = [&](int tile, int buf) {
    const int r0 = tile * 16;
    float* qb = smem + buf * 4608;
    for (int c = wave; c < 18; c += 8) {
      const int r = r0 - 1 + c;         // image row for buffer row c
      float* dst = qb + c * 256;
      if ((unsigned)r < 128u) {
        const float* src = Qg + win_base + (size_t)r * ROWSTRIDE +
                           (lane >> 3) * DIM + ch0 + (lane & 7) * 4;
        GLD_LDS16(src, dst);
      } else {
        *reinterpret_cast<float4*>(dst + lane * 4) =
            make_float4(0.f, 0.f, 0.f, 0.f);
      }
    }
  };

  // issue Q tile 0 into buf1 (latency hides under reduce), write partials
  stageQ(0, 1);
  {
    float* sc = scratch + wave * 512 + lane * 8;
    sc[0]=a00; sc[1]=a01; sc[2]=a10; sc[3]=a11;
    sc[4]=a20; sc[5]=a21; sc[6]=a30; sc[7]=a31;
  }
  __syncthreads();                       // scratch visible

  // ======== reduce 8 wave-copies + softmax over e -> A_sm[h*16+d][e] ======
  {
    const int r = t >> 4;                // 0..31 = h*16+d
    const int e = t & 15;                // 0..15
    const int h = r >> 4, d = r & 15;
    const int f = (h * 32 + (d >> 2) * 8 + (e >> 1)) * 8 + (d & 3) * 2 + (e & 1);
    float v = 0.f;
#pragma unroll
    for (int k = 0; k < 8; ++k) v += scratch[k * 512 + f];
    v *= SCALE;
    float m = v;
    m = fmaxf(m, __shfl_xor(m, 1));
    m = fmaxf(m, __shfl_xor(m, 2));
    m = fmaxf(m, __shfl_xor(m, 4));
    m = fmaxf(m, __shfl_xor(m, 8));
    v = __expf(v - m);
    float ss = v;
    ss += __shfl_xor(ss, 1);
    ss += __shfl_xor(ss, 2);
    ss += __shfl_xor(ss, 4);
    ss += __shfl_xor(ss, 8);
    A_sm[r * 16 + e] = v / ss;
  }
  __syncthreads();                       // A_sm ready; Q tile 0 drained

  // ======== Pass 2 setup: per-thread A column, conv weights, bias =========
  const int cq      = t & 7;             // channel quad (4 ch) within 32
  const int lr      = (t >> 3) & 15;     // local output row in tile
  const int quarter = t >> 7;            // wl range: quarter*2 .. +1
  const int hg = cq >> 2, e0 = (cq & 3) * 4;
  const int cg = ch0 + cq * 4;           // global channel quad base

  float4 Acol[16];
#pragma unroll
  for (int d = 0; d < 16; ++d)
    Acol[d] = *reinterpret_cast<const float4*>(&A_sm[(hg * 16 + d) * 16 + e0]);
  float4 wgt[9];
#pragma unroll
  for (int tap = 0; tap < 9; ++tap) {
    wgt[tap].x = cw[(cg + 0) * 9 + tap];
    wgt[tap].y = cw[(cg + 1) * 9 + tap];
    wgt[tap].z = cw[(cg + 2) * 9 + tap];
    wgt[tap].w = cw[(cg + 3) * 9 + tap];
  }
  const float4 bias = *reinterpret_cast<const float4*>(&cb[cg]);
  const float4 zero4 = make_float4(0.f, 0.f, 0.f, 0.f);

#define ACC(qs, d)                                                             \
  o.x += (qs) * Acol[d].x; o.y += (qs) * Acol[d].y;                            \
  o.z += (qs) * Acol[d].z; o.w += (qs) * Acol[d].w;

  // ======== Pass 2 main loop: 8 tiles of 16 rows, double-buffered =========
  int buf = 1;
  for (int tile = 0; tile < 8; ++tile) {
    if (tile < 7) stageQ(tile + 1, buf ^ 1);
    const float* Qb = smem + buf * 4608;
    const int r0 = tile * 16;
    const int w0 = quarter * 2;

    float4 cL[3], cC[3], cR[3];
    auto ldcol = [&](int cidx, float4* dv) {
#pragma unroll
      for (int dy = 0; dy < 3; ++dy)
        dv[dy] = ((unsigned)cidx < 8u)
                     ? *reinterpret_cast<const float4*>(
                           &Qb[((lr + dy) * 8 + cidx) * 32 + cq * 4])
                     : zero4;
    };
    ldcol(w0 - 1, cL);
    ldcol(w0, cC);

#pragma unroll
    for (int k = 0; k < 2; ++k) {
      const int wl = w0 + k;
      ldcol(wl + 1, cR);
      float4 o = bias;
#pragma unroll
      for (int dy = 0; dy < 3; ++dy) {
        const int t0 = dy * 3;
        o.x += cL[dy].x * wgt[t0].x + cC[dy].x * wgt[t0+1].x + cR[dy].x * wgt[t0+2].x;
        o.y += cL[dy].y * wgt[t0].y + cC[dy].y * wgt[t0+1].y + cR[dy].y * wgt[t0+2].y;
        o.z += cL[dy].z * wgt[t0].z + cC[dy].z * wgt[t0+1].z + cR[dy].z * wgt[t0+2].z;
        o.w += cL[dy].w * wgt[t0].w + cC[dy].w * wgt[t0+1].w + cR[dy].w * wgt[t0+2].w;
      }
      // attention: Q[token, hg*16..+15] . Acol  (token buffer row = lr+1)
      const float* qr = &Qb[((lr + 1) * 8 + wl) * 32 + hg * 16];
      const float4 q0 = *reinterpret_cast<const float4*>(qr + 0);
      const float4 q1 = *reinterpret_cast<const float4*>(qr + 4);
      const float4 q2 = *reinterpret_cast<const float4*>(qr + 8);
      const float4 q3 = *reinterpret_cast<const float4*>(qr + 12);
      ACC(q0.x, 0)  ACC(q0.y, 1)  ACC(q0.z, 2)  ACC(q0.w, 3)
      ACC(q1.x, 4)  ACC(q1.y, 5)  ACC(q1.z, 6)  ACC(q1.w, 7)
      ACC(q2.x, 8)  ACC(q2.y, 9)  ACC(q2.z, 10) ACC(q2.w, 11)
      ACC(q3.x, 12) ACC(q3.y, 13) ACC(q3.z, 14) ACC(q3.w, 15)

      float* dst = outp + win_base + (size_t)(r0 + lr) * ROWSTRIDE +
                   wl * DIM + cg;
      *reinterpret_cast<float4*>(dst) = o;

#pragma unroll
      for (int dy = 0; dy < 3; ++dy) { cL[dy] = cC[dy]; cC[dy] = cR[dy]; }
    }
    __syncthreads();
    buf ^= 1;
  }
#undef ACC
}

// ---------------------------------------------------------------------------
extern "C" void kernel_launch(void* const* d_in, const int* in_sizes, int n_in,
                              void* d_out, int out_size, void* d_ws,
                              size_t ws_size, hipStream_t stream) {
  const float* qkv = (const float*)d_in[0];
  const float* cw  = (const float*)d_in[1];
  const float* cb  = (const float*)d_in[2];
  const float* Qg = qkv;
  const float* Kg = qkv + (size_t)BB * L * DIM;
  const float* Vg = Kg + (size_t)BB * L * DIM;
  float* outp = (float*)d_out;

  fused_lepe<<<512, 512, 0, stream>>>(Qg, Kg, Vg, cw, cb, outp);
}

// Round 13
// 62.952 us; speedup vs baseline: 3.0224x; 1.1618x over previous
//
#include <hip/hip_runtime.h>

// ---------------------------------------------------------------------------
// EfficentLePE, block-local: block = (window w, head-pair g), 256 threads.
//   A[h] = softmax_e( SCALE * sum_n K[n,d] V[n,e] )   (16x16)
//   out[n,e] = sum_d Q[n,d] A[h][d,e] + depthwise3x3(Q)[n,e] + bias
// R4 base (best, 55.3us). Single change: attention q-quads come from the
// conv center-row register (cC[1]) + DPP quad_perm cross-lane moves instead
// of 16 extra b128 LDS reads per thread per tile (R12 profile: 9.7M LDS
// bank-conflict cycles, LDS-pipe-bound; 64-distinct-aligned-quad reads are
// provably >=8-way on this layout, so reduce reads instead of swizzling).
// Acol is loaded pre-permuted by jj=cq&3 so all register indices stay
// compile-time (no scratch).
// ---------------------------------------------------------------------------

static constexpr int BB   = 8;
static constexpr int RES  = 128;
static constexpr int DIM  = 128;
static constexpr int WSP  = 8;
static constexpr int L    = RES * RES;   // 16384
static constexpr int ROWSTRIDE = RES * DIM;
static constexpr float SCALE = 0.25f;    // HD^-0.5, HD=16

#define GLD_LDS16(g, l)                                                        \
  __builtin_amdgcn_global_load_lds(                                            \
      (const __attribute__((address_space(1))) void*)(const void*)(g),         \
      (__attribute__((address_space(3))) void*)(l), 16, 0, 0)

// DPP quad_perm helpers (VALU pipe, lanes within each aligned 4-lane group)
#define QP_XOR1 0xB1  // [1,0,3,2]
#define QP_XOR2 0x4E  // [2,3,0,1]
#define QP_XOR3 0x1B  // [3,2,1,0]
template <int CTRL>
__device__ __forceinline__ float dpp_f(float x) {
  return __builtin_bit_cast(
      float, __builtin_amdgcn_mov_dpp(__builtin_bit_cast(int, x), CTRL, 0xF,
                                      0xF, true));
}
template <int CTRL>
__device__ __forceinline__ float4 dpp_f4(float4 v) {
  return make_float4(dpp_f<CTRL>(v.x), dpp_f<CTRL>(v.y), dpp_f<CTRL>(v.z),
                     dpp_f<CTRL>(v.w));
}

__global__ __launch_bounds__(256, 2) void fused_lepe(
    const float* __restrict__ Qg, const float* __restrict__ Kg,
    const float* __restrict__ Vg, const float* __restrict__ cw,
    const float* __restrict__ cb, float* __restrict__ outp) {
  // smem map (floats):
  //  pass1: K dbuf [0,8192) (2 x 4096), V dbuf [8192,16384)
  //  scratch [0,2048)                  (after pass1; K buf dead)
  //  pass2: Qbuf0 [0,4608), Qbuf1 [4608,9216)
  //  A_sm  [16384,16896)
  __shared__ float smem[16896];
  float* const A_sm    = smem + 16384;
  float* const scratch = smem;

  const int b  = blockIdx.x;            // 0..511
  const int w  = b >> 2, g = b & 3;     // window, head-group (2 heads)
  const int bi = w >> 4, wb = w & 15;   // batch, window-col
  const int t  = threadIdx.x;
  const int wave = t >> 6, lane = t & 63;
  const size_t win_base = (size_t)(bi * L + wb * WSP) * DIM;
  const int ch0 = g * 32;               // first global channel of this group

  // ======== Pass 1: Gram = K^T V, 8 tiles of 16 image rows (R4 exact) =====
  const int h1 = lane >> 5, dq = (lane >> 3) & 3, ep = lane & 7;
  const int kaddr = h1 * 16 + dq * 4;
  const int vaddr = h1 * 16 + ep * 2;
  const int n0 = wave * 32;             // this wave's token quarter of tile

  float a00=0.f,a01=0.f,a10=0.f,a11=0.f,a20=0.f,a21=0.f,a30=0.f,a31=0.f;

  auto stageKV = [&](int tile, int buf) {
    for (int c = wave; c < 32; c += 4) {
      const int mat = c >> 4, rr = c & 15;
      const int r = tile * 16 + rr;     // image row
      const float* src = (mat ? Vg : Kg) + win_base +
                         (size_t)r * ROWSTRIDE + (lane >> 3) * DIM + ch0 +
                         (lane & 7) * 4;
      float* dst = smem + mat * 8192 + buf * 4096 + rr * 256;
      GLD_LDS16(src, dst);
    }
  };

  stageKV(0, 0);
  __syncthreads();
  for (int tt = 0; tt < 8; ++tt) {
    const int cur = tt & 1;
    if (tt < 7) stageKV(tt + 1, cur ^ 1);
    const float* Kb = smem + cur * 4096;
    const float* Vb = smem + 8192 + cur * 4096;
#pragma unroll 4
    for (int n = n0; n < n0 + 32; ++n) {
      const float4 k4 = *reinterpret_cast<const float4*>(&Kb[n * 32 + kaddr]);
      const float2 v2 = *reinterpret_cast<const float2*>(&Vb[n * 32 + vaddr]);
      a00 += k4.x * v2.x; a01 += k4.x * v2.y;
      a10 += k4.y * v2.x; a11 += k4.y * v2.y;
      a20 += k4.z * v2.x; a21 += k4.z * v2.y;
      a30 += k4.w * v2.x; a31 += k4.w * v2.y;
    }
    __syncthreads();
  }

  // ======== Q-tile staging helper (18 rows incl. halos, R4 layout) ========
  auto stageQ = [&](int tile, int buf) {
    const int r0 = tile * 16;
    float* qb = smem + buf * 4608;
    for (int c = wave; c < 18; c += 4) {
      const int r = r0 - 1 + c;         // image row for buffer row c
      float* dst = qb + c * 256;
      if ((unsigned)r < 128u) {
        const float* src = Qg + win_base + (size_t)r * ROWSTRIDE +
                           (lane >> 3) * DIM + ch0 + (lane & 7) * 4;
        GLD_LDS16(src, dst);
      } else {
        *reinterpret_cast<float4*>(dst + lane * 4) =
            make_float4(0.f, 0.f, 0.f, 0.f);
      }
    }
  };

  // issue Q tile 0 into buf1 (latency hides under reduce), write partials
  stageQ(0, 1);
  {
    float* sc = scratch + wave * 512 + lane * 8;
    sc[0]=a00; sc[1]=a01; sc[2]=a10; sc[3]=a11;
    sc[4]=a20; sc[5]=a21; sc[6]=a30; sc[7]=a31;
  }
  __syncthreads();                       // scratch visible

  // ======== reduce 4 wave-copies + softmax over e -> A_sm[h*16+d][e] ======
  {
    const int r = t >> 3, e2 = t & 7;    // r = h*16+d, e in {2e2, 2e2+1}
    const int h = r >> 4, d = r & 15;
    const int f = (h * 32 + (d >> 2) * 8 + e2) * 8 + (d & 3) * 2;
    float v0 = (scratch[f]     + scratch[512 + f]     + scratch[1024 + f]     + scratch[1536 + f]) * SCALE;
    float v1 = (scratch[f + 1] + scratch[512 + f + 1] + scratch[1024 + f + 1] + scratch[1536 + f + 1]) * SCALE;
    float m = fmaxf(v0, v1);
    m = fmaxf(m, __shfl_xor(m, 1));
    m = fmaxf(m, __shfl_xor(m, 2));
    m = fmaxf(m, __shfl_xor(m, 4));
    v0 = __expf(v0 - m); v1 = __expf(v1 - m);
    float ss = v0 + v1;
    ss += __shfl_xor(ss, 1);
    ss += __shfl_xor(ss, 2);
    ss += __shfl_xor(ss, 4);
    const float ri = 1.0f / ss;
    A_sm[r * 16 + e2 * 2 + 0] = v0 * ri;
    A_sm[r * 16 + e2 * 2 + 1] = v1 * ri;
  }
  __syncthreads();                       // A_sm ready; Q tile 0 drained

  // ======== Pass 2 setup =================================================
  const int cq   = t & 7;                // channel quad (4 ch) within 32
  const int lr   = (t >> 3) & 15;        // local output row in tile
  const int half = t >> 7;               // wl range: half*4 .. half*4+3
  const int hg = cq >> 2;                // head within group
  const int jj = cq & 3;                 // own d-quad index within head
  const int e0 = jj * 4;                 // output e-quad
  const int cg = ch0 + cq * 4;           // global channel quad base

  // Acol pre-permuted by shuffle arrival order: slot m holds A rows of
  // d-quad (jj^m); DPP xor-m delivers Q quad (jj^m).
  float4 Acol[16];
#pragma unroll
  for (int m = 0; m < 4; ++m) {
    const int dq4 = (jj ^ m) * 4;
#pragma unroll
    for (int c = 0; c < 4; ++c)
      Acol[m * 4 + c] = *reinterpret_cast<const float4*>(
          &A_sm[(hg * 16 + dq4 + c) * 16 + e0]);
  }
  float4 wgt[9];
#pragma unroll
  for (int tap = 0; tap < 9; ++tap) {
    wgt[tap].x = cw[(cg + 0) * 9 + tap];
    wgt[tap].y = cw[(cg + 1) * 9 + tap];
    wgt[tap].z = cw[(cg + 2) * 9 + tap];
    wgt[tap].w = cw[(cg + 3) * 9 + tap];
  }
  const float4 bias = *reinterpret_cast<const float4*>(&cb[cg]);
  const float4 zero4 = make_float4(0.f, 0.f, 0.f, 0.f);

#define ACC(qs, d)                                                             \
  o.x += (qs) * Acol[d].x; o.y += (qs) * Acol[d].y;                            \
  o.z += (qs) * Acol[d].z; o.w += (qs) * Acol[d].w;
#define ACC4(qv, m)                                                            \
  ACC(qv.x, (m)*4 + 0) ACC(qv.y, (m)*4 + 1) ACC(qv.z, (m)*4 + 2)               \
  ACC(qv.w, (m)*4 + 3)

  // ======== Pass 2 main loop: 8 tiles of 16 rows, double-buffered =========
  int buf = 1;
  for (int tile = 0; tile < 8; ++tile) {
    if (tile < 7) stageQ(tile + 1, buf ^ 1);
    const float* Qb = smem + buf * 4608;
    const int r0 = tile * 16;
    const int w0 = half * 4;

    float4 cL[3], cC[3], cR[3];
    auto ldcol = [&](int cidx, float4* dv) {
#pragma unroll
      for (int dy = 0; dy < 3; ++dy)
        dv[dy] = ((unsigned)cidx < 8u)
                     ? *reinterpret_cast<const float4*>(
                           &Qb[((lr + dy) * 8 + cidx) * 32 + cq * 4])
                     : zero4;
    };
    ldcol(w0 - 1, cL);
    ldcol(w0, cC);

#pragma unroll
    for (int k = 0; k < 4; ++k) {
      const int wl = w0 + k;
      ldcol(wl + 1, cR);
      float4 o = bias;
#pragma unroll
      for (int dy = 0; dy < 3; ++dy) {
        const int t0 = dy * 3;
        o.x += cL[dy].x * wgt[t0].x + cC[dy].x * wgt[t0+1].x + cR[dy].x * wgt[t0+2].x;
        o.y += cL[dy].y * wgt[t0].y + cC[dy].y * wgt[t0+1].y + cR[dy].y * wgt[t0+2].y;
        o.z += cL[dy].z * wgt[t0].z + cC[dy].z * wgt[t0+1].z + cR[dy].z * wgt[t0+2].z;
        o.w += cL[dy].w * wgt[t0].w + cC[dy].w * wgt[t0+1].w + cR[dy].w * wgt[t0+2].w;
      }
      // attention: the 4 q-quads of head hg live in this 4-lane group's
      // cC[1] registers (conv center row == attention token row).
      {
        const float4 q_own = cC[1];
        const float4 q_x1 = dpp_f4<QP_XOR1>(q_own);
        const float4 q_x2 = dpp_f4<QP_XOR2>(q_own);
        const float4 q_x3 = dpp_f4<QP_XOR3>(q_own);
        ACC4(q_own, 0)
        ACC4(q_x1, 1)
        ACC4(q_x2, 2)
        ACC4(q_x3, 3)
      }
      float* dst = outp + win_base + (size_t)(r0 + lr) * ROWSTRIDE +
                   wl * DIM + cg;
      *reinterpret_cast<float4*>(dst) = o;

#pragma unroll
      for (int dy = 0; dy < 3; ++dy) { cL[dy] = cC[dy]; cC[dy] = cR[dy]; }
    }
    __syncthreads();
    buf ^= 1;
  }
#undef ACC
#undef ACC4
}

// ---------------------------------------------------------------------------
extern "C" void kernel_launch(void* const* d_in, const int* in_sizes, int n_in,
                              void* d_out, int out_size, void* d_ws,
                              size_t ws_size, hipStream_t stream) {
  const float* qkv = (const float*)d_in[0];
  const float* cw  = (const float*)d_in[1];
  const float* cb  = (const float*)d_in[2];
  const float* Qg = qkv;
  const float* Kg = qkv + (size_t)BB * L * DIM;
  const float* Vg = Kg + (size_t)BB * L * DIM;
  float* outp = (float*)d_out;

  fused_lepe<<<512, 256, 0, stream>>>(Qg, Kg, Vg, cw, cb, outp);
}